// Round 3
// baseline (1272.380 us; speedup 1.0000x reference)
//
#include <hip/hip_runtime.h>

// FusedLoRA: x[4,4096,4096] f32; 3x (A[4096,8], B[8,4096]) f32
// out[16384][12288] = concat_l( (x @ A_l) @ B_l ), scale = 1.0
//
// Two kernels via d_ws:
//  Phase 1: xa[16384][24] = x @ [A0|A1|A2]    read-bound (268 MB x)   ~55 us
//  Phase 2: out = xa @ blockdiag(B0,B1,B2)    write-bound (805 MB)    ~135 us

#define DIM       4096
#define M_ROWS    16384
#define RANK      8
#define NC        24
#define OUT_COLS  12288

// ---------------- Phase 1 ----------------
#define KC             512       // At = 24*512*4 = 48 KB LDS -> 3 blocks/CU
#define ROWS_PER_WAVE  4
#define ROWS_PER_BLOCK 16

__launch_bounds__(256, 3)
__global__ void lora_xa_kernel(const float* __restrict__ x,
                               const float* __restrict__ A0,
                               const float* __restrict__ A1,
                               const float* __restrict__ A2,
                               float* __restrict__ xa) {
  // Transposed A chunk: compute read At[c][4*lane] is 16B-contiguous across lanes
  // -> conflict-free ds_read_b128.
  __shared__ float At[NC][KC];

  const int tid  = threadIdx.x;
  const int lane = tid & 63;
  const int wave = tid >> 6;
  const int row0 = blockIdx.x * ROWS_PER_BLOCK + wave * ROWS_PER_WAVE;

  float acc[ROWS_PER_WAVE][NC];
#pragma unroll
  for (int r = 0; r < ROWS_PER_WAVE; ++r)
#pragma unroll
    for (int c = 0; c < NC; ++c) acc[r][c] = 0.f;

  for (int kb = 0; kb < DIM; kb += KC) {
    // ---- prefetch this chunk's x BEFORE the staging barrier ----
    // (independent of LDS; overlaps HBM latency with A staging + barrier)
    float4 xv[2][ROWS_PER_WAVE];
#pragma unroll
    for (int step = 0; step < 2; ++step)
#pragma unroll
      for (int r = 0; r < ROWS_PER_WAVE; ++r)
        xv[step][r] = *(const float4*)(x + (size_t)(row0 + r) * DIM + kb +
                                       step * 256 + 4 * lane);

    // ---- stage A chunk transposed into LDS ----
    // per lora: KC*8 floats = 1024 float4; 3 loras = 3072 float4 / 256 thr = 12
#pragma unroll
    for (int j = 0; j < 12; ++j) {
      const int l   = j >> 2;                    // compile-time after unroll
      const int idx = tid + (j & 3) * 256;       // float4 index within lora chunk
      const int dof = idx >> 1;                  // k offset in chunk
      const int rq  = (idx & 1) * 4;             // rank quad: 0 or 4
      const float* Ap = (l == 0) ? A0 : (l == 1) ? A1 : A2;
      const float4 v = *(const float4*)(Ap + (size_t)(kb + dof) * RANK + rq);
      At[l * RANK + rq + 0][dof] = v.x;
      At[l * RANK + rq + 1][dof] = v.y;
      At[l * RANK + rq + 2][dof] = v.z;
      At[l * RANK + rq + 3][dof] = v.w;
    }
    __syncthreads();

#pragma unroll
    for (int step = 0; step < 2; ++step) {
      const int kl = step * 256 + 4 * lane;
#pragma unroll
      for (int c = 0; c < NC; ++c) {
        const float4 av = *(const float4*)(&At[c][kl]);
#pragma unroll
        for (int r = 0; r < ROWS_PER_WAVE; ++r) {
          acc[r][c] = fmaf(xv[step][r].x, av.x, acc[r][c]);
          acc[r][c] = fmaf(xv[step][r].y, av.y, acc[r][c]);
          acc[r][c] = fmaf(xv[step][r].z, av.z, acc[r][c]);
          acc[r][c] = fmaf(xv[step][r].w, av.w, acc[r][c]);
        }
      }
    }
    __syncthreads();
  }

  // 64-lane butterfly reduction per (row, col)
#pragma unroll
  for (int r = 0; r < ROWS_PER_WAVE; ++r)
#pragma unroll
    for (int c = 0; c < NC; ++c) {
      float v = acc[r][c];
#pragma unroll
      for (int off = 32; off > 0; off >>= 1) v += __shfl_xor(v, off, 64);
      acc[r][c] = v;
    }

  float outv[ROWS_PER_WAVE];
#pragma unroll
  for (int c = 0; c < NC; ++c)
#pragma unroll
    for (int r = 0; r < ROWS_PER_WAVE; ++r)
      if (lane == c) outv[r] = acc[r][c];

  if (lane < NC) {
#pragma unroll
    for (int r = 0; r < ROWS_PER_WAVE; ++r)
      xa[(size_t)(row0 + r) * NC + lane] = outv[r];
  }
}

// ---------------- Phase 2 ----------------
#define ROW_TILE 256             // xa tile in LDS; grid 12 x 64 = 768 blocks (1 pass)

__launch_bounds__(256, 4)
__global__ void lora_expand_kernel(const float* __restrict__ xa,
                                   const float* __restrict__ B0,
                                   const float* __restrict__ B1,
                                   const float* __restrict__ B2,
                                   float* __restrict__ out) {
  // stride 12 floats: 16B-aligned for b128, write banks 2-way (free), reads broadcast
  __shared__ float xs[ROW_TILE][12];

  const int tid   = threadIdx.x;
  const int ctile = blockIdx.x;                 // 0..11
  const int rtile = blockIdx.y;                 // 0..63
  const int l     = ctile >> 2;
  const int oc    = ctile * 1024 + tid * 4;     // global out col
  const int ob    = oc - l * DIM;               // col within B_l
  const float* B  = (l == 0) ? B0 : (l == 1) ? B1 : B2;
  const int row0  = rtile * ROW_TILE;

  // B fragment in registers for the whole block (32 VGPR); L2-resident loads
  float4 b[RANK];
#pragma unroll
  for (int r = 0; r < RANK; ++r)
    b[r] = *(const float4*)(B + (size_t)r * DIM + ob);

  // stage this block's xa rows (its lora's 8-float slice) into LDS: 1 row/thread
  {
    const float* src = xa + (size_t)(row0 + tid) * NC + l * RANK;
    const float4 v0 = *(const float4*)(src);
    const float4 v1 = *(const float4*)(src + 4);
    *(float4*)(&xs[tid][0]) = v0;
    *(float4*)(&xs[tid][4]) = v1;
  }
  __syncthreads();

#pragma unroll 8
  for (int i = 0; i < ROW_TILE; ++i) {
    const float4 s0 = *(const float4*)(&xs[i][0]);   // LDS broadcast
    const float4 s1 = *(const float4*)(&xs[i][4]);
    const float s[8] = {s0.x, s0.y, s0.z, s0.w, s1.x, s1.y, s1.z, s1.w};

    float4 av = {0.f, 0.f, 0.f, 0.f};
#pragma unroll
    for (int r = 0; r < RANK; ++r) {
      av.x = fmaf(s[r], b[r].x, av.x);
      av.y = fmaf(s[r], b[r].y, av.y);
      av.z = fmaf(s[r], b[r].z, av.z);
      av.w = fmaf(s[r], b[r].w, av.w);
    }
    *(float4*)(out + (size_t)(row0 + i) * OUT_COLS + oc) = av;
  }
}

extern "C" void kernel_launch(void* const* d_in, const int* in_sizes, int n_in,
                              void* d_out, int out_size, void* d_ws, size_t ws_size,
                              hipStream_t stream) {
  const float* x  = (const float*)d_in[0];
  const float* A0 = (const float*)d_in[1];
  const float* B0 = (const float*)d_in[2];
  const float* A1 = (const float*)d_in[3];
  const float* B1 = (const float*)d_in[4];
  const float* A2 = (const float*)d_in[5];
  const float* B2 = (const float*)d_in[6];
  float* out = (float*)d_out;
  float* xa  = (float*)d_ws;                    // 16384*24*4 = 1.5 MB

  if (ws_size < (size_t)M_ROWS * NC * sizeof(float)) return;

  lora_xa_kernel<<<dim3(M_ROWS / ROWS_PER_BLOCK), dim3(256), 0, stream>>>(
      x, A0, A1, A2, xa);
  lora_expand_kernel<<<dim3(12, M_ROWS / ROW_TILE), dim3(256), 0, stream>>>(
      xa, B0, B1, B2, out);
}

// Round 5
// 1085.891 us; speedup vs baseline: 1.1717x; 1.1717x over previous
//
#include <hip/hip_runtime.h>

// FusedLoRA: x[4,4096,4096] f32; 3x (A[4096,8], B[8,4096]) f32
// out[16384][12288] = concat_l( (x @ A_l) @ B_l ), scale = 1.0
//
// Phase 1: xa[16384][24] = x @ [A0|A1|A2]   read-bound  (268 MB x)  ~55 us
// Phase 2: out = xa @ blockdiag(B0,B1,B2)   write-bound (805 MB)    ~140 us
//
// R3 lesson: ROWS_PER_WAVE=4 (acc=96 VGPR) + prefetch + bounds(256,3) spilled.
// Fix: ROWS_PER_WAVE=2 -> acc=48 VGPR; prefetch fits under the ~170-VGPR cap.
// R4 lesson: __builtin_nontemporal_store needs a native clang vector type,
// not HIP_vector_type<float,4> -> use ext_vector_type(4).

#define DIM       4096
#define M_ROWS    16384
#define RANK      8
#define NC        24
#define OUT_COLS  12288

typedef float floatx4 __attribute__((ext_vector_type(4)));

// ---------------- Phase 1 ----------------
#define KC             512       // At = 24*512*4 = 48 KB LDS -> 3 blocks/CU
#define ROWS_PER_WAVE  2
#define ROWS_PER_BLOCK 8         // 4 waves * 2 rows

__launch_bounds__(256, 3)
__global__ void lora_xa_kernel(const float* __restrict__ x,
                               const float* __restrict__ A0,
                               const float* __restrict__ A1,
                               const float* __restrict__ A2,
                               float* __restrict__ xa) {
  // Transposed A chunk: compute read At[c][4*lane] is 16B-contiguous across
  // lanes -> conflict-free ds_read_b128.
  __shared__ float At[NC][KC];

  const int tid  = threadIdx.x;
  const int lane = tid & 63;
  const int wave = tid >> 6;
  const int row0 = blockIdx.x * ROWS_PER_BLOCK + wave * ROWS_PER_WAVE;

  float acc[ROWS_PER_WAVE][NC];                  // 48 VGPR
#pragma unroll
  for (int r = 0; r < ROWS_PER_WAVE; ++r)
#pragma unroll
    for (int c = 0; c < NC; ++c) acc[r][c] = 0.f;

  for (int kb = 0; kb < DIM; kb += KC) {
    // prefetch this chunk's x before the staging barrier (16 VGPR)
    float4 xv[2][ROWS_PER_WAVE];
#pragma unroll
    for (int step = 0; step < 2; ++step)
#pragma unroll
      for (int r = 0; r < ROWS_PER_WAVE; ++r)
        xv[step][r] = *(const float4*)(x + (size_t)(row0 + r) * DIM + kb +
                                       step * 256 + 4 * lane);

    // stage A chunk transposed into LDS:
    // per lora KC*8 floats = 1024 float4; 3 loras = 3072 float4 / 256 thr = 12
#pragma unroll
    for (int j = 0; j < 12; ++j) {
      const int l   = j >> 2;                    // compile-time after unroll
      const int idx = tid + (j & 3) * 256;       // float4 index within lora chunk
      const int dof = idx >> 1;                  // k offset in chunk
      const int rq  = (idx & 1) * 4;             // rank quad: 0 or 4
      const float* Ap = (l == 0) ? A0 : (l == 1) ? A1 : A2;
      const float4 v = *(const float4*)(Ap + (size_t)(kb + dof) * RANK + rq);
      At[l * RANK + rq + 0][dof] = v.x;
      At[l * RANK + rq + 1][dof] = v.y;
      At[l * RANK + rq + 2][dof] = v.z;
      At[l * RANK + rq + 3][dof] = v.w;
    }
    __syncthreads();

#pragma unroll
    for (int step = 0; step < 2; ++step) {
      const int kl = step * 256 + 4 * lane;
#pragma unroll
      for (int c = 0; c < NC; ++c) {
        const float4 av = *(const float4*)(&At[c][kl]);
#pragma unroll
        for (int r = 0; r < ROWS_PER_WAVE; ++r) {
          acc[r][c] = fmaf(xv[step][r].x, av.x, acc[r][c]);
          acc[r][c] = fmaf(xv[step][r].y, av.y, acc[r][c]);
          acc[r][c] = fmaf(xv[step][r].z, av.z, acc[r][c]);
          acc[r][c] = fmaf(xv[step][r].w, av.w, acc[r][c]);
        }
      }
    }
    __syncthreads();
  }

  // 64-lane butterfly reduction per (row, col)
#pragma unroll
  for (int r = 0; r < ROWS_PER_WAVE; ++r)
#pragma unroll
    for (int c = 0; c < NC; ++c) {
      float v = acc[r][c];
#pragma unroll
      for (int off = 32; off > 0; off >>= 1) v += __shfl_xor(v, off, 64);
      acc[r][c] = v;
    }

  float outv[ROWS_PER_WAVE];
#pragma unroll
  for (int c = 0; c < NC; ++c)
#pragma unroll
    for (int r = 0; r < ROWS_PER_WAVE; ++r)
      if (lane == c) outv[r] = acc[r][c];

  if (lane < NC) {
#pragma unroll
    for (int r = 0; r < ROWS_PER_WAVE; ++r)
      xa[(size_t)(row0 + r) * NC + lane] = outv[r];
  }
}

// ---------------- Phase 2 ---------------- (r1 structure + NT stores)
#define ROW_TILE        128
#define COLS_PER_BLOCK  1024     // 256 threads * float4; grid 12 x 128

__launch_bounds__(256, 4)
__global__ void lora_expand_kernel(const float* __restrict__ xa,
                                   const float* __restrict__ B0,
                                   const float* __restrict__ B1,
                                   const float* __restrict__ B2,
                                   float* __restrict__ out) {
  const int ctile = blockIdx.x;                 // 0..11
  const int rtile = blockIdx.y;                 // 0..127
  const int l     = ctile >> 2;
  const int o     = (ctile & 3) * COLS_PER_BLOCK + threadIdx.x * 4;
  const float* B  = (l == 0) ? B0 : (l == 1) ? B1 : B2;

  float4 b[RANK];                               // 32 VGPR, L2-resident loads
#pragma unroll
  for (int r = 0; r < RANK; ++r)
    b[r] = *(const float4*)(B + (size_t)r * DIM + o);

  const int row0    = rtile * ROW_TILE;
  const size_t ocol = (size_t)l * DIM + o;

#pragma unroll 8
  for (int i = 0; i < ROW_TILE; ++i) {
    const int row = row0 + i;
    const float* xr = xa + (size_t)row * NC + l * RANK;  // 16B-aligned
    const float4 s0 = *(const float4*)(xr);      // wave-uniform -> L1 broadcast
    const float4 s1 = *(const float4*)(xr + 4);
    const float s[8] = {s0.x, s0.y, s0.z, s0.w, s1.x, s1.y, s1.z, s1.w};

    floatx4 acc = {0.f, 0.f, 0.f, 0.f};
#pragma unroll
    for (int r = 0; r < RANK; ++r) {
      acc.x = fmaf(s[r], b[r].x, acc.x);
      acc.y = fmaf(s[r], b[r].y, acc.y);
      acc.z = fmaf(s[r], b[r].z, acc.z);
      acc.w = fmaf(s[r], b[r].w, acc.w);
    }
    // streaming store: don't thrash L2 (B lives there)
    __builtin_nontemporal_store(acc, (floatx4*)(out + (size_t)row * OUT_COLS + ocol));
  }
}

extern "C" void kernel_launch(void* const* d_in, const int* in_sizes, int n_in,
                              void* d_out, int out_size, void* d_ws, size_t ws_size,
                              hipStream_t stream) {
  const float* x  = (const float*)d_in[0];
  const float* A0 = (const float*)d_in[1];
  const float* B0 = (const float*)d_in[2];
  const float* A1 = (const float*)d_in[3];
  const float* B1 = (const float*)d_in[4];
  const float* A2 = (const float*)d_in[5];
  const float* B2 = (const float*)d_in[6];
  float* out = (float*)d_out;
  float* xa  = (float*)d_ws;                    // 16384*24*4 = 1.5 MB

  if (ws_size < (size_t)M_ROWS * NC * sizeof(float)) return;

  lora_xa_kernel<<<dim3(M_ROWS / ROWS_PER_BLOCK), dim3(256), 0, stream>>>(
      x, A0, A1, A2, xa);
  lora_expand_kernel<<<dim3(12, M_ROWS / ROW_TILE), dim3(256), 0, stream>>>(
      xa, B0, B1, B2, out);
}